// Round 8
// baseline (38.910 us; speedup 1.0000x reference)
//
#include <hip/hip_runtime.h>

typedef __attribute__((ext_vector_type(8))) short short8;
typedef __attribute__((ext_vector_type(16))) float f32x16;

#define NROWS 32768        // B*H*W
#define NELEM 262144       // B*C*H*W
#define KCB   8192
#define NKC   8            // k-chunks (grid y)
#define ENTC  1024         // entries per chunk (32 KB staged)
#define RPB   512          // rows per scan block (8 waves x 64)
#define MSKP  0xFFFFE000u

// round-to-nearest-even fp32 -> bf16 (finite values only)
static __device__ __forceinline__ short to_bf16(float x) {
    unsigned u = __float_as_uint(x);
    unsigned r = (u + 0x7FFFu + ((u >> 16) & 1u)) >> 16;
    return (short)r;
}

// Prep: codebook into 32-entry-group layout for mfma_32x32x16 B-operand:
// group g occupies 1KB: bytes [0,512) = entries' ch0..7 (16B each, k=0..7),
// bytes [512,1024) = entries' [-0.5||e||^2, 0x7] (k=8..15). Also pack z rows
// (8 bf16) and zero the loss slot.
__global__ __launch_bounds__(256) void vq_prep(
    const float* __restrict__ z, const float* __restrict__ cb,
    short8* __restrict__ cbb32, short8* __restrict__ pka, float* __restrict__ out)
{
    int gid = blockIdx.x * 256 + threadIdx.x;
    if (gid == 0) out[NELEM] = 0.0f;
    if (gid < KCB) {
        const float4* p = (const float4*)(cb + (size_t)gid * 8);
        float4 a = p[0], b = p[1];
        float h = -0.5f * (a.x*a.x + a.y*a.y + a.z*a.z + a.w*a.w
                         + b.x*b.x + b.y*b.y + b.z*b.z + b.w*b.w);
        short8 lo = { to_bf16(a.x), to_bf16(a.y), to_bf16(a.z), to_bf16(a.w),
                      to_bf16(b.x), to_bf16(b.y), to_bf16(b.z), to_bf16(b.w) };
        short8 hi = { to_bf16(h), 0, 0, 0, 0, 0, 0, 0 };
        cbb32[(gid >> 5) * 64 + (gid & 31)]      = lo;
        cbb32[(gid >> 5) * 64 + 32 + (gid & 31)] = hi;
    } else {
        int n = gid - KCB;
        int bb = n >> 12, hw = n & 4095;
        const float* zp = z + (size_t)bb * 32768 + hw;
        short8 v = { to_bf16(zp[0]),     to_bf16(zp[4096]),
                     to_bf16(zp[8192]),  to_bf16(zp[12288]),
                     to_bf16(zp[16384]), to_bf16(zp[20480]),
                     to_bf16(zp[24576]), to_bf16(zp[28672]) };
        pka[n] = v;
    }
}

// Scan: block (rb, kc) stages chunk kc (32 KB) into LDS ONCE (single barrier),
// then 8 waves x 64 private rows scan it with mfma_f32_32x32x16_bf16.
// Per lane: entry col = lane&31; 16 acc regs = 16 rows. Partial best per row
// (packed score|inv-idx) written to ws.
__global__ __launch_bounds__(512, 4) void vq_scan(
    const short8* __restrict__ cbb32, const short8* __restrict__ pka,
    float* __restrict__ part)
{
    __shared__ char sb[32768];

    const int tid  = threadIdx.x;
    const int lane = tid & 63;
    const int w    = tid >> 6;
    const int kc   = blockIdx.y;
    const int growbase = blockIdx.x * RPB + w * 64;   // this wave's 64 rows

    // ---- stage chunk: 8 waves x 4 x 1KB linear global_load_lds ----
    const char* gsrc = (const char*)cbb32 + (size_t)kc * 32768;
    #pragma unroll
    for (int s = 0; s < 4; ++s) {
        const int go = (w * 4 + s) * 1024;
        __builtin_amdgcn_global_load_lds(
            (const __attribute__((address_space(1))) void*)(gsrc + go + lane * 16),
            (__attribute__((address_space(3))) void*)(sb + go), 16, 0, 0);
    }

    // ---- A frags: rows = lane&31 (lanes 0..31, k0-7 = channels);
    //      lanes 32..63 carry k8 = 1.0 (pairs with -0.5||e||^2) ----
    short8 af0, af1;
    if (lane < 32) {
        af0 = pka[growbase + lane];
        af1 = pka[growbase + 32 + lane];
    } else {
        short8 one = {(short)0x3F80, 0, 0, 0, 0, 0, 0, 0};
        af0 = one; af1 = one;
    }

    float bp0[16], bp1[16];
    #pragma unroll
    for (int r = 0; r < 16; ++r) {
        bp0[r] = __uint_as_float(0xFF800000u);   // -inf
        bp1[r] = __uint_as_float(0xFF800000u);
    }

    const unsigned ivb = 8191u - (unsigned)(kc * ENTC) - (unsigned)(lane & 31);
    const f32x16 z16 = {0.f,0.f,0.f,0.f,0.f,0.f,0.f,0.f,
                        0.f,0.f,0.f,0.f,0.f,0.f,0.f,0.f};

    __syncthreads();   // compiler drains vmcnt before barrier -> LDS ready

    // ---- 16 group-pairs (64 entries each): 2 ds_read + 4 MFMA + pack/max3 ----
    #pragma unroll 4
    for (int pr = 0; pr < 16; ++pr) {
        const char* p = sb + pr * 2048 + lane * 16;
        short8 b0 = *(const short8*)(p);
        short8 b1 = *(const short8*)(p + 1024);
        const unsigned iv0 = ivb - (unsigned)(pr * 64);
        const unsigned iv1 = iv0 - 32u;

        f32x16 d0 = __builtin_amdgcn_mfma_f32_32x32x16_bf16(af0, b0, z16, 0, 0, 0);
        f32x16 d1 = __builtin_amdgcn_mfma_f32_32x32x16_bf16(af0, b1, z16, 0, 0, 0);
        #pragma unroll
        for (int r = 0; r < 16; ++r) {
            float p0 = __uint_as_float((__float_as_uint(d0[r]) & MSKP) | iv0);
            float p1 = __uint_as_float((__float_as_uint(d1[r]) & MSKP) | iv1);
            bp0[r] = fmaxf(fmaxf(p0, p1), bp0[r]);            // v_max3_f32
        }
        f32x16 e0 = __builtin_amdgcn_mfma_f32_32x32x16_bf16(af1, b0, z16, 0, 0, 0);
        f32x16 e1 = __builtin_amdgcn_mfma_f32_32x32x16_bf16(af1, b1, z16, 0, 0, 0);
        #pragma unroll
        for (int r = 0; r < 16; ++r) {
            float p0 = __uint_as_float((__float_as_uint(e0[r]) & MSKP) | iv0);
            float p1 = __uint_as_float((__float_as_uint(e1[r]) & MSKP) | iv1);
            bp1[r] = fmaxf(fmaxf(p0, p1), bp1[r]);
        }
    }

    // ---- reduce over 32 entry-cols (lanes l and l^d share rows for d<32) ----
    #pragma unroll
    for (int d = 1; d < 32; d <<= 1) {
        #pragma unroll
        for (int r = 0; r < 16; ++r) {
            bp0[r] = fmaxf(bp0[r], __shfl_xor(bp0[r], d));
            bp1[r] = fmaxf(bp1[r], __shfl_xor(bp1[r], d));
        }
    }

    if ((lane & 31) == 0) {
        const int h = lane >> 5;
        float* pt = part + (size_t)kc * NROWS + growbase;
        #pragma unroll
        for (int r = 0; r < 16; ++r) {
            const int m = (r & 3) + ((r >> 2) << 3) + (h << 2);  // C/D row map
            pt[m]      = bp0[r];
            pt[32 + m] = bp1[r];
        }
    }
}

// Emit: 8-way max over chunk partials, gather code, write z_q (NCHW), loss.
__global__ __launch_bounds__(256) void vq_emit(
    const float* __restrict__ z, const float* __restrict__ cb,
    const float* __restrict__ part, float* __restrict__ out)
{
    const int n = blockIdx.x * 256 + threadIdx.x;
    float m = part[n];
    #pragma unroll
    for (int kc = 1; kc < NKC; ++kc)
        m = fmaxf(m, part[(size_t)kc * NROWS + n]);
    const int k = 8191 - (int)(__float_as_uint(m) & 8191u);

    const float4* ep = (const float4*)(cb + (size_t)k * 8);
    float4 ea = ep[0], eb = ep[1];
    float e[8] = {ea.x, ea.y, ea.z, ea.w, eb.x, eb.y, eb.z, eb.w};

    const size_t o = (size_t)(n >> 12) * 32768 + (size_t)(n & 4095);
    float sq = 0.0f;
    #pragma unroll
    for (int c = 0; c < 8; ++c) {
        float zz = z[o + (size_t)c * 4096];
        out[o + (size_t)c * 4096] = e[c];
        float d = e[c] - zz;
        sq = fmaf(d, d, sq);
    }
    #pragma unroll
    for (int off = 32; off > 0; off >>= 1) sq += __shfl_down(sq, off);
    if ((threadIdx.x & 63) == 0)
        atomicAdd(out + NELEM, sq * (1.25f / (float)NELEM));
}

extern "C" void kernel_launch(void* const* d_in, const int* in_sizes, int n_in,
                              void* d_out, int out_size, void* d_ws, size_t ws_size,
                              hipStream_t stream)
{
    const float* z  = (const float*)d_in[0];   // [8, 8, 64, 64] fp32
    const float* cb = (const float*)d_in[1];   // [8192, 8] fp32
    float* out = (float*)d_out;                // 262144 z_q + 1 loss
    short8* cbb32 = (short8*)d_ws;                            // 256 KB
    short8* pka   = (short8*)((char*)d_ws + 256 * 1024);      // 512 KB
    float*  part  = (float*)((char*)d_ws + 768 * 1024);       // 1 MB partials

    vq_prep<<<(KCB + NROWS) / 256, 256, 0, stream>>>(z, cb, cbb32, pka, out);
    dim3 gs(NROWS / RPB, NKC);
    vq_scan<<<gs, 512, 0, stream>>>(cbb32, pka, part);
    vq_emit<<<NROWS / 256, 256, 0, stream>>>(z, cb, part, out);
}